// Round 5
// baseline (207.939 us; speedup 1.0000x reference)
//
#include <hip/hip_runtime.h>

#define Bsz 8
#define Nsz 2048
#define Dsz 512
#define Hsz 1024
#define K3D 1536   // 3*Dsz

typedef __attribute__((ext_vector_type(8))) short short8;
typedef __attribute__((ext_vector_type(4))) float f32x4;

// ---------------------------------------------------------------------------
// helpers
// ---------------------------------------------------------------------------
static __device__ __forceinline__ unsigned short f2bf(float f) {
    unsigned u = __builtin_bit_cast(unsigned, f);
    unsigned r = (u + 0x7FFFu + ((u >> 16) & 1u)) >> 16;   // RNE
    return (unsigned short)r;
}
static __device__ __forceinline__ float bf2f(unsigned short u) {
    return __builtin_bit_cast(float, (unsigned)u << 16);
}
static __device__ __forceinline__ void gld16(const void* g, void* l) {
    __builtin_amdgcn_global_load_lds(
        (const __attribute__((address_space(1))) void*)g,
        (__attribute__((address_space(3))) void*)l, 16, 0, 0);
}

// ===========================================================================
// FAST PATH
// ===========================================================================

// CD constants: C_j = sum_h ln_g*pw_j ; D_j = sum_h ln_b*pw_j
__global__ __launch_bounds__(256) void consts_kernel(
    const float* __restrict__ lng, const float* __restrict__ lnb,
    const float* __restrict__ pw, float* __restrict__ CD)
{
    int tid = threadIdx.x;
    float c0 = 0.f, c1 = 0.f, d0 = 0.f, d1 = 0.f;
    for (int h = tid; h < Hsz; h += 256) {
        float g = lng[h], b = lnb[h];
        float w0 = pw[2 * h], w1 = pw[2 * h + 1];
        c0 = fmaf(g, w0, c0); c1 = fmaf(g, w1, c1);
        d0 = fmaf(b, w0, d0); d1 = fmaf(b, w1, d1);
    }
    #pragma unroll
    for (int m = 32; m >= 1; m >>= 1) {
        c0 += __shfl_xor(c0, m, 64); c1 += __shfl_xor(c1, m, 64);
        d0 += __shfl_xor(d0, m, 64); d1 += __shfl_xor(d1, m, 64);
    }
    __shared__ float red[4][4];
    int w = tid >> 6;
    if ((tid & 63) == 0) { red[w][0] = c0; red[w][1] = c1; red[w][2] = d0; red[w][3] = d1; }
    __syncthreads();
    if (tid == 0) {
        CD[0] = red[0][0] + red[1][0] + red[2][0] + red[3][0];
        CD[1] = red[0][1] + red[1][1] + red[2][1] + red[3][1];
        CD[2] = red[0][2] + red[1][2] + red[2][2] + red[3][2];
        CD[3] = red[0][3] + red[1][3] + red[2][3] + red[3][3];
    }
}

__global__ __launch_bounds__(256) void colconst_kernel(
    const float* __restrict__ lng, const float* __restrict__ pw,
    float* __restrict__ gq0, float* __restrict__ gq1)
{
    int h = blockIdx.x * 256 + threadIdx.x;
    float g = lng[h];
    gq0[h] = g * pw[2 * h];
    gq1[h] = g * pw[2 * h + 1];
}

// x (fp32 [B][N][D]) -> q-major bf16 hi/lo: xs[b][c16][q4][row2050][16B].
// c = 32-elem k-chunk, q = 8-elem quarter within the chunk (the MFMA k-quarter
// a lane with l>>4==q reads). Padded rows 0 and 2049 are zero.
__global__ __launch_bounds__(256) void convert_x_kernel(
    const float* __restrict__ x, unsigned short* __restrict__ xsh,
    unsigned short* __restrict__ xsl)
{
    int tid = threadIdx.x;
    int r = blockIdx.x * 4 + (tid >> 6);         // padded row id 0..16399
    int e = tid & 63;                            // 8 elems each
    int b  = r / 2050;
    int rp = r - b * 2050;
    int c  = e >> 2;                             // k0-chunk 0..15
    int qq = e & 3;                              // k-quarter 0..3
    size_t dst = ((((size_t)b * 16 + c) * 4 + qq) * 2050 + rp) * 16;
    short8 hv, lv;
    if (rp == 0 || rp == 2049) {
        #pragma unroll
        for (int u = 0; u < 8; ++u) { hv[u] = 0; lv[u] = 0; }
    } else {
        const float* p = x + ((size_t)b * Nsz + (rp - 1)) * Dsz + e * 8;
        float4 v0 = *(const float4*)p;
        float4 v1 = *(const float4*)(p + 4);
        float vv[8] = { v0.x, v0.y, v0.z, v0.w, v1.x, v1.y, v1.z, v1.w };
        #pragma unroll
        for (int u = 0; u < 8; ++u) {
            unsigned short h = f2bf(vv[u]);
            hv[u] = (short)h;
            lv[u] = (short)f2bf(vv[u] - bf2f(h));
        }
    }
    *(short8*)((char*)xsh + dst) = hv;
    *(short8*)((char*)xsl + dst) = lv;
}

// conv_w [H][D][3] fp32 -> q-major bf16 hi/lo: ws[s48][q4][h1024][16B],
// s = t*16 + c; quarter q holds k-elems d = c*32 + q*8 .. +7 of tap t.
__global__ __launch_bounds__(256) void convert_w_kernel(
    const float* __restrict__ cw, unsigned short* __restrict__ wsh,
    unsigned short* __restrict__ wsl)
{
    int gid = blockIdx.x * 256 + threadIdx.x;    // 0..49151
    int s = gid >> 10, h = gid & 1023;
    int t = s >> 4, c = s & 15;
    const float* src = cw + (size_t)h * K3D + (size_t)c * 96 + t;  // (c*32+j)*3 + t
    short hv[32], lv[32];
    #pragma unroll
    for (int j = 0; j < 32; ++j) {
        float v = src[3 * j];
        unsigned short hi = f2bf(v);
        hv[j] = (short)hi;
        lv[j] = (short)f2bf(v - bf2f(hi));
    }
    #pragma unroll
    for (int m = 0; m < 4; ++m) {
        size_t dst = (((size_t)s * 4 + m) * 1024 + h) * 16;
        *(short8*)((char*)wsh + dst) = *(short8*)&hv[m * 8];
        *(short8*)((char*)wsl + dst) = *(short8*)&lv[m * 8];
    }
}

// Fused bf16x3 GEMM, q-major staging, 2-phase double-buffered prefetch.
// Tile 128x128, 4 waves (2x2 of 64x64), BK=32, 48 steps (3 taps x 16 chunks).
// LDS: 2 bufs x {Ah,Al,Bh,Bl} x 8KB = 64 KB; each region [q4][row128][16B]:
// staging (wave w fills q-plane w, lane-linear) and ds_read_b128 frags
// (16-lane group = 256 contiguous B = 32 banks at 2-way) are conflict-free.
__global__ __launch_bounds__(256, 2) void gemm5_kernel(
    const unsigned short* __restrict__ xsh, const unsigned short* __restrict__ xsl,
    const unsigned short* __restrict__ wsh, const unsigned short* __restrict__ wsl,
    const float* __restrict__ cb, const float* __restrict__ gq0,
    const float* __restrict__ gq1, float* __restrict__ part)
{
    __shared__ __align__(16) char lds[65536];

    int tid = threadIdx.x;
    // XCD-aware swizzle (bijective: 1024 % 8 == 0): blocks sharing an A-panel
    // (same mt, all 8 ntb) become consecutive on one XCD -> L2-resident A.
    int bid0 = blockIdx.x;
    int bid  = (bid0 & 7) * 128 + (bid0 >> 3);
    int mt  = bid >> 3;            // 0..127
    int ntb = bid & 7;             // col block
    int bb  = mt >> 4;             // batch
    int n0  = (mt & 15) * 128;     // batch-local row base (padded-row base)
    int n0c = ntb * 128;           // col base
    int n0g = bb * Nsz + n0;       // global output row base

    int l = tid & 63, w = tid >> 6;
    int wlo = w * 2048;            // wave stages its own q-plane (w) of each region
    int wrow = (w >> 1) * 64, wcol = (w & 1) * 64;
    int r = l & 15, q = l >> 4;
    int aoff_r = q * 2048 + (wrow + r) * 16;
    int boff_r = q * 2048 + (wcol + r) * 16;

    // per-thread staging source bases (lane-linear: +l*16 -> contiguous 1KB/instr)
    const char* pAh0 = (const char*)xsh + ((size_t)(bb * 64 + w) * 2050 + n0 + l) * 16;
    const char* pAl0 = (const char*)xsl + ((size_t)(bb * 64 + w) * 2050 + n0 + l) * 16;
    const char* pBh0 = (const char*)wsh + ((size_t)w * 1024 + n0c + l) * 16;
    const char* pBl0 = (const char*)wsl + ((size_t)w * 1024 + n0c + l) * 16;

    f32x4 acc[4][4];
    #pragma unroll
    for (int i = 0; i < 4; ++i)
        #pragma unroll
        for (int j = 0; j < 4; ++j) acc[i][j] = (f32x4){0.f, 0.f, 0.f, 0.f};

#define STAGE4(lb, aoff, boff) do {                                  \
    gld16(pAh0 + (aoff),        (lb) + wlo);                         \
    gld16(pAh0 + (aoff) + 1024, (lb) + wlo + 1024);                  \
    gld16(pAl0 + (aoff),        (lb) + 8192 + wlo);                  \
    gld16(pAl0 + (aoff) + 1024, (lb) + 8192 + wlo + 1024);           \
    gld16(pBh0 + (boff),        (lb) + 16384 + wlo);                 \
    gld16(pBh0 + (boff) + 1024, (lb) + 16384 + wlo + 1024);          \
    gld16(pBl0 + (boff),        (lb) + 24576 + wlo);                 \
    gld16(pBl0 + (boff) + 1024, (lb) + 24576 + wlo + 1024);          \
} while (0)

    // prologue: stage step 0 into buf 0  (step s: chunk c = s&15, tap t = s>>4)
    STAGE4(lds, 0, 0);
    __syncthreads();

    for (int s = 0; s < 48; ++s) {
        char* cbuf = lds + (s & 1) * 32768;
        if (s < 47) {
            int sn = s + 1;
            char* nb = lds + (sn & 1) * 32768;
            int aoff = (sn & 15) * 131200 + (sn >> 4) * 16;  // chunk jump + tap row shift
            int boff = sn << 16;                             // sn * 4 planes * 16KB
            STAGE4(nb, aoff, boff);
        }
        short8 ah[4], al[4], bh[4], bl[4];
        #pragma unroll
        for (int i = 0; i < 4; ++i) {
            ah[i] = *(const short8*)(cbuf + aoff_r + i * 256);
            al[i] = *(const short8*)(cbuf + 8192 + aoff_r + i * 256);
        }
        #pragma unroll
        for (int j = 0; j < 4; ++j) {
            bh[j] = *(const short8*)(cbuf + 16384 + boff_r + j * 256);
            bl[j] = *(const short8*)(cbuf + 24576 + boff_r + j * 256);
        }
        #pragma unroll
        for (int i = 0; i < 4; ++i)
            #pragma unroll
            for (int j = 0; j < 4; ++j) {
                acc[i][j] = __builtin_amdgcn_mfma_f32_16x16x32_bf16(ah[i], bh[j], acc[i][j], 0, 0, 0);
                acc[i][j] = __builtin_amdgcn_mfma_f32_16x16x32_bf16(ah[i], bl[j], acc[i][j], 0, 0, 0);
                acc[i][j] = __builtin_amdgcn_mfma_f32_16x16x32_bf16(al[i], bh[j], acc[i][j], 0, 0, 0);
            }
        __syncthreads();   // drains vmcnt(0) (next buf staged) + protects cbuf
    }
#undef STAGE4

    // epilogue: bias + relu + per-row stats over this wave's 64 cols.
    // Each wave writes its OWN slot: ntb*8 + (w&1)*4 (16 slots of 4 floats/row).
    float cbv[4], g0v[4], g1v[4];
    #pragma unroll
    for (int j = 0; j < 4; ++j) {
        int col = n0c + wcol + j * 16 + r;
        cbv[j] = cb[col]; g0v[j] = gq0[col]; g1v[j] = gq1[col];
    }
    int slot = ntb * 8 + (w & 1) * 4;
    #pragma unroll
    for (int i = 0; i < 4; ++i) {
        #pragma unroll
        for (int reg = 0; reg < 4; ++reg) {
            float v0 = 0.f, v2 = 0.f, va = 0.f, vb = 0.f;
            #pragma unroll
            for (int j = 0; j < 4; ++j) {
                float v = acc[i][j][reg] + cbv[j];
                v = fmaxf(v, 0.f);
                v0 += v;
                v2 = fmaf(v, v, v2);
                va = fmaf(v, g0v[j], va);
                vb = fmaf(v, g1v[j], vb);
            }
            #pragma unroll
            for (int msk = 1; msk < 16; msk <<= 1) {
                v0 += __shfl_xor(v0, msk, 64); v2 += __shfl_xor(v2, msk, 64);
                va += __shfl_xor(va, msk, 64); vb += __shfl_xor(vb, msk, 64);
            }
            if (r == 0) {
                int rowg = n0g + wrow + i * 16 + q * 4 + reg;
                *(f32x4*)(part + (size_t)rowg * 64 + slot) = (f32x4){v0, v2, va, vb};
            }
        }
    }
}

// finish LN + proj + argmax per row (deterministic reduction over 16 slots)
__global__ __launch_bounds__(256) void probs_kernel(
    const float* __restrict__ part, const float* __restrict__ CD,
    const float* __restrict__ pb, float* __restrict__ probs,
    int* __restrict__ gout)
{
    int row = blockIdx.x * 256 + threadIdx.x;
    float S0 = 0.f, S2 = 0.f, Sa = 0.f, Sb = 0.f;
    const float4* p = (const float4*)(part + (size_t)row * 64);
    #pragma unroll
    for (int c = 0; c < 16; ++c) {
        float4 v = p[c];
        S0 += v.x; S2 += v.y; Sa += v.z; Sb += v.w;
    }
    float mu  = S0 * (1.0f / Hsz);
    float var = S2 * (1.0f / Hsz) - mu * mu;
    float rsq = 1.0f / sqrtf(var + 1e-5f);
    float p0 = fmaf(rsq, Sa - mu * CD[0], CD[2] + pb[0]);
    float p1 = fmaf(rsq, Sb - mu * CD[1], CD[3] + pb[1]);
    probs[(size_t)row * 2]     = p0;
    probs[(size_t)row * 2 + 1] = p1;
    gout[row] = (p1 > p0) ? 1 : 0;
}

// ===========================================================================
// FALLBACK PATH (round-1 kernel, known-passing)
// ===========================================================================
#define ROWS 64
#define CCH 128
#define NCC (Hsz / CCH)
#define DSTEP 32

__global__ __launch_bounds__(256) void conv_ln_proj_kernel(
    const float* __restrict__ x, const float* __restrict__ cw,
    const float* __restrict__ cb, const float* __restrict__ lng,
    const float* __restrict__ pw, const float* __restrict__ pb,
    const float* __restrict__ CD, float* __restrict__ probs,
    int* __restrict__ gout)
{
    __shared__ float Xl[DSTEP][66];
    __shared__ float Bl[3][DSTEP][CCH];
    __shared__ float Sl[ROWS][4];

    int tid = threadIdx.x;
    int blk = blockIdx.x;
    int b  = blk >> 5;
    int n0 = (blk & 31) * ROWS;
    int rg = tid >> 5;
    int cg = tid & 31;
    int sr = tid >> 2;
    int sq = tid & 3;
    const float* xb = x + (size_t)b * Nsz * Dsz;

    float s0[8], s2[8], sa[8], sb[8];
    #pragma unroll
    for (int i = 0; i < 8; ++i) { s0[i] = 0.f; s2[i] = 0.f; sa[i] = 0.f; sb[i] = 0.f; }

    for (int cc = 0; cc < NCC; ++cc) {
        float cbv[4], gq0[4], gq1[4];
        {
            int hb = cc * CCH + cg * 4;
            #pragma unroll
            for (int j = 0; j < 4; ++j) {
                int h = hb + j;
                cbv[j] = cb[h];
                float gg = lng[h];
                gq0[j] = gg * pw[2 * h];
                gq1[j] = gg * pw[2 * h + 1];
            }
        }
        float acc[8][4];
        #pragma unroll
        for (int i = 0; i < 8; ++i)
            #pragma unroll
            for (int j = 0; j < 4; ++j) acc[i][j] = 0.f;

        for (int ds = 0; ds < Dsz / DSTEP; ++ds) {
            int d0 = ds * DSTEP;
            __syncthreads();
            {
                int n = n0 - 1 + sr;
                float4 v0 = make_float4(0.f, 0.f, 0.f, 0.f), v1 = v0;
                if ((unsigned)n < (unsigned)Nsz) {
                    const float* p = xb + (size_t)n * Dsz + d0 + sq * 8;
                    v0 = *(const float4*)p;
                    v1 = *(const float4*)(p + 4);
                }
                int dd = sq * 8;
                Xl[dd + 0][sr] = v0.x; Xl[dd + 1][sr] = v0.y;
                Xl[dd + 2][sr] = v0.z; Xl[dd + 3][sr] = v0.w;
                Xl[dd + 4][sr] = v1.x; Xl[dd + 5][sr] = v1.y;
                Xl[dd + 6][sr] = v1.z; Xl[dd + 7][sr] = v1.w;
                if (tid < 8) {
                    int r2 = 64 + (tid >> 2);
                    int q2 = tid & 3;
                    int n2 = n0 - 1 + r2;
                    float4 u0 = make_float4(0.f, 0.f, 0.f, 0.f), u1 = u0;
                    if ((unsigned)n2 < (unsigned)Nsz) {
                        const float* p2 = xb + (size_t)n2 * Dsz + d0 + q2 * 8;
                        u0 = *(const float4*)p2;
                        u1 = *(const float4*)(p2 + 4);
                    }
                    int dd2 = q2 * 8;
                    Xl[dd2 + 0][r2] = u0.x; Xl[dd2 + 1][r2] = u0.y;
                    Xl[dd2 + 2][r2] = u0.z; Xl[dd2 + 3][r2] = u0.w;
                    Xl[dd2 + 4][r2] = u1.x; Xl[dd2 + 5][r2] = u1.y;
                    Xl[dd2 + 6][r2] = u1.z; Xl[dd2 + 7][r2] = u1.w;
                }
            }
            {
                int hl = tid >> 1;
                int half = tid & 1;
                const float* p = cw + (size_t)(cc * CCH + hl) * K3D + (size_t)d0 * 3 + half * 48;
                #pragma unroll
                for (int mq = 0; mq < 12; ++mq) {
                    float4 v = *(const float4*)(p + mq * 4);
                    float vv[4] = { v.x, v.y, v.z, v.w };
                    #pragma unroll
                    for (int e = 0; e < 4; ++e) {
                        int c  = mq * 4 + e;
                        int dl = half * 16 + c / 3;
                        int kk = c % 3;
                        Bl[kk][dl][hl] = vv[e];
                    }
                }
            }
            __syncthreads();
            #pragma unroll 4
            for (int dd = 0; dd < DSTEP; ++dd) {
                float a[10];
                #pragma unroll
                for (int j = 0; j < 10; ++j) a[j] = Xl[dd][rg * 8 + j];
                #pragma unroll
                for (int kk = 0; kk < 3; ++kk) {
                    float4 bv = *(const float4*)&Bl[kk][dd][cg * 4];
                    #pragma unroll
                    for (int i = 0; i < 8; ++i) {
                        float av = a[i + kk];
                        acc[i][0] = fmaf(av, bv.x, acc[i][0]);
                        acc[i][1] = fmaf(av, bv.y, acc[i][1]);
                        acc[i][2] = fmaf(av, bv.z, acc[i][2]);
                        acc[i][3] = fmaf(av, bv.w, acc[i][3]);
                    }
                }
            }
        }
        #pragma unroll
        for (int i = 0; i < 8; ++i) {
            #pragma unroll
            for (int j = 0; j < 4; ++j) {
                float v = acc[i][j] + cbv[j];
                v = fmaxf(v, 0.f);
                s0[i] += v;
                s2[i] = fmaf(v, v, s2[i]);
                sa[i] = fmaf(v, gq0[j], sa[i]);
                sb[i] = fmaf(v, gq1[j], sb[i]);
            }
        }
    }
    #pragma unroll
    for (int i = 0; i < 8; ++i) {
        float v0 = s0[i], v2 = s2[i], va = sa[i], vb = sb[i];
        #pragma unroll
        for (int mm = 16; mm >= 1; mm >>= 1) {
            v0 += __shfl_xor(v0, mm, 64); v2 += __shfl_xor(v2, mm, 64);
            va += __shfl_xor(va, mm, 64); vb += __shfl_xor(vb, mm, 64);
        }
        if (cg == 0) {
            int rr = rg * 8 + i;
            Sl[rr][0] = v0; Sl[rr][1] = v2; Sl[rr][2] = va; Sl[rr][3] = vb;
        }
    }
    __syncthreads();
    if (tid < ROWS) {
        int rr = tid, n = n0 + rr;
        float S0 = Sl[rr][0], S2 = Sl[rr][1], Sa = Sl[rr][2], Sb = Sl[rr][3];
        float mu  = S0 * (1.0f / Hsz);
        float var = S2 * (1.0f / Hsz) - mu * mu;
        float rsq = 1.0f / sqrtf(var + 1e-5f);
        float p0 = fmaf(rsq, Sa - mu * CD[0], CD[2] + pb[0]);
        float p1 = fmaf(rsq, Sb - mu * CD[1], CD[3] + pb[1]);
        size_t ro = (size_t)(b * Nsz + n);
        probs[ro * 2]     = p0;
        probs[ro * 2 + 1] = p1;
        gout[ro] = (p1 > p0) ? 1 : 0;
    }
}

// ===========================================================================
// shared tail kernels
// ===========================================================================
__global__ __launch_bounds__(256) void bounds_kernel(
    const int* __restrict__ g, float* __restrict__ vlist, int* __restrict__ Kb)
{
    int b = blockIdx.x, tid = threadIdx.x;
    int base = tid * 8;
    int f[8]; float val[8]; int lsum = 0;
    #pragma unroll
    for (int u = 0; u < 8; ++u) {
        int i = base + u;
        int nz;
        if (i == Nsz - 1) nz = 1;
        else if (i == 0)  nz = 0;
        else              nz = (g[b * Nsz + i] == 0) ? 1 : 0;
        f[u] = nz;
        val[u] = (i == Nsz - 1) ? (float)Nsz : (float)(i + 1);
        lsum += nz;
    }
    int lane = tid & 63, w = tid >> 6;
    int sc = lsum;
    #pragma unroll
    for (int off = 1; off < 64; off <<= 1) {
        int t = __shfl_up(sc, off, 64);
        if (lane >= off) sc += t;
    }
    __shared__ int wsum[4];
    if (lane == 63) wsum[w] = sc;
    __syncthreads();
    int woff = 0;
    #pragma unroll
    for (int k = 0; k < 4; ++k) if (k < w) woff += wsum[k];
    int pos = woff + (sc - lsum);
    #pragma unroll
    for (int u = 0; u < 8; ++u) {
        if (f[u]) { vlist[b * Nsz + pos] = val[u]; pos++; }
    }
    if (tid == 255) Kb[b] = woff + sc;
}

__global__ __launch_bounds__(256) void fill_kernel(
    const float* __restrict__ vlist, const int* __restrict__ Kb,
    float* __restrict__ mat)
{
    int blk = blockIdx.x;
    int b = blk >> 11, j = blk & 2047;
    int K = Kb[b];
    float c = (j < K) ? vlist[b * Nsz + j] : 0.0f;
    float a = (j == 0) ? 0.0f : vlist[b * Nsz + j - 1];
    int tc = threadIdx.x * 8;
    float o[8];
    #pragma unroll
    for (int e = 0; e < 8; ++e) {
        float t = (float)(tc + e + 1);
        o[e] = (t > a && t <= c) ? 1.0f : 0.0f;
    }
    float4* p = (float4*)(mat + (size_t)blk * Nsz + tc);
    p[0] = make_float4(o[0], o[1], o[2], o[3]);
    p[1] = make_float4(o[4], o[5], o[6], o[7]);
}

// ===========================================================================
extern "C" void kernel_launch(void* const* d_in, const int* in_sizes, int n_in,
                              void* d_out, int out_size, void* d_ws, size_t ws_size,
                              hipStream_t stream)
{
    const float* x      = (const float*)d_in[0];
    const float* conv_w = (const float*)d_in[1];
    const float* conv_b = (const float*)d_in[2];
    const float* ln_g   = (const float*)d_in[3];
    const float* ln_b   = (const float*)d_in[4];
    const float* proj_w = (const float*)d_in[5];
    const float* proj_b = (const float*)d_in[6];

    float* out = (float*)d_out;
    char*  wsb = (char*)d_ws;

    // fast-path workspace layout
    size_t cur = 0;
    auto take = [&](size_t b) { size_t r = cur; cur = (cur + b + 255) & ~(size_t)255; return r; };
    size_t oCD  = take(16);
    size_t oGQ0 = take(Hsz * 4);
    size_t oGQ1 = take(Hsz * 4);
    size_t oKb  = take(32);
    size_t oG   = take((size_t)Bsz * Nsz * 4);
    size_t oV   = take((size_t)Bsz * Nsz * 4);
    size_t oPart= take((size_t)Bsz * Nsz * 64 * 4);
    size_t oXh  = take((size_t)Bsz * 16 * 4 * 2050 * 16);   // xs hi (q-major)
    size_t oXl  = take((size_t)Bsz * 16 * 4 * 2050 * 16);   // xs lo
    size_t oWh  = take((size_t)48 * 4 * 1024 * 16);         // ws hi
    size_t oWl  = take((size_t)48 * 4 * 1024 * 16);         // ws lo
    bool fast = ws_size >= cur;

    if (fast) {
        float* CD    = (float*)(wsb + oCD);
        float* gq0   = (float*)(wsb + oGQ0);
        float* gq1   = (float*)(wsb + oGQ1);
        int*   Kb    = (int*)  (wsb + oKb);
        int*   g     = (int*)  (wsb + oG);
        float* vlist = (float*)(wsb + oV);
        float* part  = (float*)(wsb + oPart);
        unsigned short* xsh = (unsigned short*)(wsb + oXh);
        unsigned short* xsl = (unsigned short*)(wsb + oXl);
        unsigned short* wsh = (unsigned short*)(wsb + oWh);
        unsigned short* wsl = (unsigned short*)(wsb + oWl);

        consts_kernel<<<1, 256, 0, stream>>>(ln_g, ln_b, proj_w, CD);
        colconst_kernel<<<Hsz / 256, 256, 0, stream>>>(ln_g, proj_w, gq0, gq1);
        convert_x_kernel<<<Bsz * 2050 / 4, 256, 0, stream>>>(x, xsh, xsl);
        convert_w_kernel<<<48 * Hsz / 256, 256, 0, stream>>>(conv_w, wsh, wsl);
        gemm5_kernel<<<(Bsz * Nsz / 128) * (Hsz / 128), 256, 0, stream>>>(
            xsh, xsl, wsh, wsl, conv_b, gq0, gq1, part);
        probs_kernel<<<Bsz * Nsz / 256, 256, 0, stream>>>(part, CD, proj_b, out, g);
        bounds_kernel<<<Bsz, 256, 0, stream>>>(g, vlist, Kb);
        fill_kernel<<<Bsz * Nsz, 256, 0, stream>>>(vlist, Kb, out + (size_t)Bsz * Nsz * 2);
    } else {
        // round-1 fallback layout
        float* wf  = (float*)d_ws;
        int*   wi  = (int*)d_ws;
        float* CD    = wf;
        int*   Kb    = wi + 4;
        int*   g     = wi + 16;
        float* vlist = wf + 16 + Bsz * Nsz;

        consts_kernel<<<1, 256, 0, stream>>>(ln_g, ln_b, proj_w, CD);
        conv_ln_proj_kernel<<<Bsz * Nsz / ROWS, 256, 0, stream>>>(
            x, conv_w, conv_b, ln_g, proj_w, proj_b, CD, out, g);
        bounds_kernel<<<Bsz, 256, 0, stream>>>(g, vlist, Kb);
        fill_kernel<<<Bsz * Nsz, 256, 0, stream>>>(vlist, Kb, out + (size_t)Bsz * Nsz * 2);
    }
}

// Round 6
// 200.964 us; speedup vs baseline: 1.0347x; 1.0347x over previous
//
#include <hip/hip_runtime.h>

#define Bsz 8
#define Nsz 2048
#define Dsz 512
#define Hsz 1024
#define K3D 1536   // 3*Dsz

typedef __attribute__((ext_vector_type(8))) short short8;
typedef __attribute__((ext_vector_type(4))) float f32x4;

// ---------------------------------------------------------------------------
// helpers
// ---------------------------------------------------------------------------
static __device__ __forceinline__ unsigned short f2bf(float f) {
    unsigned u = __builtin_bit_cast(unsigned, f);
    unsigned r = (u + 0x7FFFu + ((u >> 16) & 1u)) >> 16;   // RNE
    return (unsigned short)r;
}
static __device__ __forceinline__ float bf2f(unsigned short u) {
    return __builtin_bit_cast(float, (unsigned)u << 16);
}
static __device__ __forceinline__ void gld16(const void* g, void* l) {
    __builtin_amdgcn_global_load_lds(
        (const __attribute__((address_space(1))) void*)g,
        (__attribute__((address_space(3))) void*)l, 16, 0, 0);
}

// ===========================================================================
// FAST PATH
// ===========================================================================

// prep: convert_w (blocks 0..191) + consts (block 192) + colconst (193..196)
__global__ __launch_bounds__(256) void prep_kernel(
    const float* __restrict__ cw, unsigned short* __restrict__ wsh,
    unsigned short* __restrict__ wsl,
    const float* __restrict__ lng, const float* __restrict__ lnb,
    const float* __restrict__ pw, float* __restrict__ CD,
    float* __restrict__ gq0, float* __restrict__ gq1)
{
    __shared__ float red[4][4];
    int blk = blockIdx.x, tid = threadIdx.x;
    if (blk < 192) {
        // conv_w [H][D][3] fp32 -> q-major bf16 hi/lo: ws[s48][q4][h1024][16B]
        int gid = blk * 256 + tid;                   // 0..49151
        int s = gid >> 10, h = gid & 1023;
        int t = s >> 4, c = s & 15;
        const float* src = cw + (size_t)h * K3D + (size_t)c * 96 + t;
        short hv[32], lv[32];
        #pragma unroll
        for (int j = 0; j < 32; ++j) {
            float v = src[3 * j];
            unsigned short hi = f2bf(v);
            hv[j] = (short)hi;
            lv[j] = (short)f2bf(v - bf2f(hi));
        }
        #pragma unroll
        for (int m = 0; m < 4; ++m) {
            size_t dst = (((size_t)s * 4 + m) * 1024 + h) * 16;
            *(short8*)((char*)wsh + dst) = *(short8*)&hv[m * 8];
            *(short8*)((char*)wsl + dst) = *(short8*)&lv[m * 8];
        }
    } else if (blk == 192) {
        float c0 = 0.f, c1 = 0.f, d0 = 0.f, d1 = 0.f;
        for (int h = tid; h < Hsz; h += 256) {
            float g = lng[h], b = lnb[h];
            float w0 = pw[2 * h], w1 = pw[2 * h + 1];
            c0 = fmaf(g, w0, c0); c1 = fmaf(g, w1, c1);
            d0 = fmaf(b, w0, d0); d1 = fmaf(b, w1, d1);
        }
        #pragma unroll
        for (int m = 32; m >= 1; m >>= 1) {
            c0 += __shfl_xor(c0, m, 64); c1 += __shfl_xor(c1, m, 64);
            d0 += __shfl_xor(d0, m, 64); d1 += __shfl_xor(d1, m, 64);
        }
        int w = tid >> 6;
        if ((tid & 63) == 0) { red[w][0] = c0; red[w][1] = c1; red[w][2] = d0; red[w][3] = d1; }
        __syncthreads();
        if (tid == 0) {
            CD[0] = red[0][0] + red[1][0] + red[2][0] + red[3][0];
            CD[1] = red[0][1] + red[1][1] + red[2][1] + red[3][1];
            CD[2] = red[0][2] + red[1][2] + red[2][2] + red[3][2];
            CD[3] = red[0][3] + red[1][3] + red[2][3] + red[3][3];
        }
    } else {
        int h = (blk - 193) * 256 + tid;
        float g = lng[h];
        gq0[h] = g * pw[2 * h];
        gq1[h] = g * pw[2 * h + 1];
    }
}

// x (fp32 [B][N][D]) -> q-major bf16 hi/lo: xs[b][c16][q4][row2050][16B].
__global__ __launch_bounds__(256) void convert_x_kernel(
    const float* __restrict__ x, unsigned short* __restrict__ xsh,
    unsigned short* __restrict__ xsl)
{
    int tid = threadIdx.x;
    int r = blockIdx.x * 4 + (tid >> 6);         // padded row id 0..16399
    int e = tid & 63;                            // 8 elems each
    int b  = r / 2050;
    int rp = r - b * 2050;
    int c  = e >> 2;                             // k0-chunk 0..15
    int qq = e & 3;                              // k-quarter 0..3
    size_t dst = ((((size_t)b * 16 + c) * 4 + qq) * 2050 + rp) * 16;
    short8 hv, lv;
    if (rp == 0 || rp == 2049) {
        #pragma unroll
        for (int u = 0; u < 8; ++u) { hv[u] = 0; lv[u] = 0; }
    } else {
        const float* p = x + ((size_t)b * Nsz + (rp - 1)) * Dsz + e * 8;
        float4 v0 = *(const float4*)p;
        float4 v1 = *(const float4*)(p + 4);
        float vv[8] = { v0.x, v0.y, v0.z, v0.w, v1.x, v1.y, v1.z, v1.w };
        #pragma unroll
        for (int u = 0; u < 8; ++u) {
            unsigned short h = f2bf(vv[u]);
            hv[u] = (short)h;
            lv[u] = (short)f2bf(vv[u] - bf2f(h));
        }
    }
    *(short8*)((char*)xsh + dst) = hv;
    *(short8*)((char*)xsl + dst) = lv;
}

// Fused bf16x3 GEMM, q-major staging, 2-sub-phase counted-vmcnt pipeline.
// Tile 128x128, 4 waves (2x2 of 64x64), BK=32, 48 steps (3 taps x 16 chunks).
// LDS: 4 rotating 16KB buffers: hi[2] = {Ah,Bh}, lo[2] = {Al,Bl}; each region
// [q4][row128][16B] (staging lane-linear, ds_read_b128 conflict-free).
// Each phase: issue STAGE for (phase+2) -> s_waitcnt vmcnt(8) (counted, never
// 0 in main loop) -> raw s_barrier -> ds_read -> setprio(1) MFMA setprio(0).
__global__ __launch_bounds__(256, 2) void gemm6_kernel(
    const unsigned short* __restrict__ xsh, const unsigned short* __restrict__ xsl,
    const unsigned short* __restrict__ wsh, const unsigned short* __restrict__ wsl,
    const float* __restrict__ cb, const float* __restrict__ gq0,
    const float* __restrict__ gq1, float* __restrict__ part)
{
    __shared__ __align__(16) char lds[65536];

    int tid = threadIdx.x;
    // XCD-aware swizzle (bijective: 1024 % 8 == 0)
    int bid0 = blockIdx.x;
    int bid  = (bid0 & 7) * 128 + (bid0 >> 3);
    int mt  = bid >> 3;            // 0..127
    int ntb = bid & 7;             // col block
    int bb  = mt >> 4;             // batch
    int n0  = (mt & 15) * 128;     // batch-local row base (padded-row base)
    int n0c = ntb * 128;           // col base
    int n0g = bb * Nsz + n0;       // global output row base

    int l = tid & 63, w = tid >> 6;
    int wlo = w * 2048;            // wave stages its own q-plane (w) of each region
    int wrow = (w >> 1) * 64, wcol = (w & 1) * 64;
    int r = l & 15, q = l >> 4;
    int aoff_r = q * 2048 + (wrow + r) * 16;
    int boff_r = q * 2048 + (wcol + r) * 16;

    // per-thread staging source bases (lane-linear: +l*16 -> contiguous 1KB/instr)
    const char* pAh0 = (const char*)xsh + ((size_t)(bb * 64 + w) * 2050 + n0 + l) * 16;
    const char* pAl0 = (const char*)xsl + ((size_t)(bb * 64 + w) * 2050 + n0 + l) * 16;
    const char* pBh0 = (const char*)wsh + ((size_t)w * 1024 + n0c + l) * 16;
    const char* pBl0 = (const char*)wsl + ((size_t)w * 1024 + n0c + l) * 16;

    f32x4 acc[4][4];
    #pragma unroll
    for (int i = 0; i < 4; ++i)
        #pragma unroll
        for (int j = 0; j < 4; ++j) acc[i][j] = (f32x4){0.f, 0.f, 0.f, 0.f};

    short8 ah[4], bh[4], al[4], bl[4];

// byte offsets into the step-major global layouts for step sn
#define AOFF(sn) (((sn) & 15) * 131200 + ((sn) >> 4) * 16)
#define BOFF(sn) ((sn) * 65536)
#define STAGE_HI(lb, sn) do {                                    \
    gld16(pAh0 + AOFF(sn),        (lb) + wlo);                   \
    gld16(pAh0 + AOFF(sn) + 1024, (lb) + wlo + 1024);            \
    gld16(pBh0 + BOFF(sn),        (lb) + 8192 + wlo);            \
    gld16(pBh0 + BOFF(sn) + 1024, (lb) + 8192 + wlo + 1024);     \
} while (0)
#define STAGE_LO(lb, sn) do {                                    \
    gld16(pAl0 + AOFF(sn),        (lb) + wlo);                   \
    gld16(pAl0 + AOFF(sn) + 1024, (lb) + wlo + 1024);            \
    gld16(pBl0 + BOFF(sn),        (lb) + 8192 + wlo);            \
    gld16(pBl0 + BOFF(sn) + 1024, (lb) + 8192 + wlo + 1024);     \
} while (0)
// P1: hh terms (per-acc order: hh first — matches prior rounds bit-exactly)
#define P1_BODY(cb_) do {                                                         \
    _Pragma("unroll") for (int i = 0; i < 4; ++i)                                 \
        ah[i] = *(const short8*)((cb_) + aoff_r + i * 256);                       \
    _Pragma("unroll") for (int j = 0; j < 4; ++j)                                 \
        bh[j] = *(const short8*)((cb_) + 8192 + boff_r + j * 256);                \
    __builtin_amdgcn_s_setprio(1);                                                \
    _Pragma("unroll") for (int i = 0; i < 4; ++i)                                 \
        _Pragma("unroll") for (int j = 0; j < 4; ++j)                             \
            acc[i][j] = __builtin_amdgcn_mfma_f32_16x16x32_bf16(ah[i], bh[j], acc[i][j], 0, 0, 0); \
    __builtin_amdgcn_s_setprio(0);                                                \
} while (0)
// P2: hl then lh terms (per-acc order: += hl, += lh — matches prior rounds)
#define P2_BODY(cb_) do {                                                         \
    _Pragma("unroll") for (int i = 0; i < 4; ++i)                                 \
        al[i] = *(const short8*)((cb_) + aoff_r + i * 256);                       \
    _Pragma("unroll") for (int j = 0; j < 4; ++j)                                 \
        bl[j] = *(const short8*)((cb_) + 8192 + boff_r + j * 256);                \
    __builtin_amdgcn_s_setprio(1);                                                \
    _Pragma("unroll") for (int i = 0; i < 4; ++i)                                 \
        _Pragma("unroll") for (int j = 0; j < 4; ++j)                             \
            acc[i][j] = __builtin_amdgcn_mfma_f32_16x16x32_bf16(ah[i], bl[j], acc[i][j], 0, 0, 0); \
    _Pragma("unroll") for (int i = 0; i < 4; ++i)                                 \
        _Pragma("unroll") for (int j = 0; j < 4; ++j)                             \
            acc[i][j] = __builtin_amdgcn_mfma_f32_16x16x32_bf16(al[i], bh[j], acc[i][j], 0, 0, 0); \
    __builtin_amdgcn_s_setprio(0);                                                \
} while (0)

    // prologue: hi(0) -> hibuf0, lo(0) -> lobuf0  (8 outstanding)
    STAGE_HI(lds, 0);
    STAGE_LO(lds + 32768, 0);

    for (int s = 0; s < 47; ++s) {
        char* hb  = lds + (s & 1) * 16384;
        char* lb2 = lds + 32768 + (s & 1) * 16384;
        char* hbn = lds + ((s + 1) & 1) * 16384;
        char* lbn = lds + 32768 + ((s + 1) & 1) * 16384;
        // --- P1 ---
        STAGE_HI(hbn, s + 1);
        asm volatile("s_waitcnt vmcnt(8)" ::: "memory");  // hi(s) done; lo(s)+hi(s+1) in flight
        __builtin_amdgcn_s_barrier();
        asm volatile("" ::: "memory");
        P1_BODY(hb);
        // --- P2 ---
        STAGE_LO(lbn, s + 1);
        asm volatile("s_waitcnt vmcnt(8)" ::: "memory");  // lo(s) done; hi/lo(s+1) in flight
        __builtin_amdgcn_s_barrier();
        asm volatile("" ::: "memory");
        P2_BODY(lb2);
    }
    {   // tail step s = 47 (no new issues; drain 4 -> 0)
        char* hb  = lds + 16384;   // 47&1 = 1
        char* lb2 = lds + 32768 + 16384;
        asm volatile("s_waitcnt vmcnt(4)" ::: "memory");
        __builtin_amdgcn_s_barrier();
        asm volatile("" ::: "memory");
        P1_BODY(hb);
        asm volatile("s_waitcnt vmcnt(0)" ::: "memory");
        __builtin_amdgcn_s_barrier();
        asm volatile("" ::: "memory");
        P2_BODY(lb2);
    }
#undef AOFF
#undef BOFF
#undef STAGE_HI
#undef STAGE_LO
#undef P1_BODY
#undef P2_BODY

    // epilogue: bias + relu + per-row stats over this wave's 64 cols.
    float cbv[4], g0v[4], g1v[4];
    #pragma unroll
    for (int j = 0; j < 4; ++j) {
        int col = n0c + wcol + j * 16 + r;
        cbv[j] = cb[col]; g0v[j] = gq0[col]; g1v[j] = gq1[col];
    }
    int slot = ntb * 8 + (w & 1) * 4;
    #pragma unroll
    for (int i = 0; i < 4; ++i) {
        #pragma unroll
        for (int reg = 0; reg < 4; ++reg) {
            float v0 = 0.f, v2 = 0.f, va = 0.f, vb = 0.f;
            #pragma unroll
            for (int j = 0; j < 4; ++j) {
                float v = acc[i][j][reg] + cbv[j];
                v = fmaxf(v, 0.f);
                v0 += v;
                v2 = fmaf(v, v, v2);
                va = fmaf(v, g0v[j], va);
                vb = fmaf(v, g1v[j], vb);
            }
            #pragma unroll
            for (int msk = 1; msk < 16; msk <<= 1) {
                v0 += __shfl_xor(v0, msk, 64); v2 += __shfl_xor(v2, msk, 64);
                va += __shfl_xor(va, msk, 64); vb += __shfl_xor(vb, msk, 64);
            }
            if (r == 0) {
                int rowg = n0g + wrow + i * 16 + q * 4 + reg;
                *(f32x4*)(part + (size_t)rowg * 64 + slot) = (f32x4){v0, v2, va, vb};
            }
        }
    }
}

// finish LN + proj + argmax per row (deterministic reduction over 16 slots)
__global__ __launch_bounds__(256) void probs_kernel(
    const float* __restrict__ part, const float* __restrict__ CD,
    const float* __restrict__ pb, float* __restrict__ probs,
    int* __restrict__ gout)
{
    int row = blockIdx.x * 256 + threadIdx.x;
    float S0 = 0.f, S2 = 0.f, Sa = 0.f, Sb = 0.f;
    const float4* p = (const float4*)(part + (size_t)row * 64);
    #pragma unroll
    for (int c = 0; c < 16; ++c) {
        float4 v = p[c];
        S0 += v.x; S2 += v.y; Sa += v.z; Sb += v.w;
    }
    float mu  = S0 * (1.0f / Hsz);
    float var = S2 * (1.0f / Hsz) - mu * mu;
    float rsq = 1.0f / sqrtf(var + 1e-5f);
    float p0 = fmaf(rsq, Sa - mu * CD[0], CD[2] + pb[0]);
    float p1 = fmaf(rsq, Sb - mu * CD[1], CD[3] + pb[1]);
    probs[(size_t)row * 2]     = p0;
    probs[(size_t)row * 2 + 1] = p1;
    gout[row] = (p1 > p0) ? 1 : 0;
}

// ===========================================================================
// FALLBACK PATH (round-1 kernel, known-passing)
// ===========================================================================
#define ROWS 64
#define CCH 128
#define NCC (Hsz / CCH)
#define DSTEP 32

__global__ __launch_bounds__(256) void consts_kernel(
    const float* __restrict__ lng, const float* __restrict__ lnb,
    const float* __restrict__ pw, float* __restrict__ CD)
{
    int tid = threadIdx.x;
    float c0 = 0.f, c1 = 0.f, d0 = 0.f, d1 = 0.f;
    for (int h = tid; h < Hsz; h += 256) {
        float g = lng[h], b = lnb[h];
        float w0 = pw[2 * h], w1 = pw[2 * h + 1];
        c0 = fmaf(g, w0, c0); c1 = fmaf(g, w1, c1);
        d0 = fmaf(b, w0, d0); d1 = fmaf(b, w1, d1);
    }
    #pragma unroll
    for (int m = 32; m >= 1; m >>= 1) {
        c0 += __shfl_xor(c0, m, 64); c1 += __shfl_xor(c1, m, 64);
        d0 += __shfl_xor(d0, m, 64); d1 += __shfl_xor(d1, m, 64);
    }
    __shared__ float red[4][4];
    int w = tid >> 6;
    if ((tid & 63) == 0) { red[w][0] = c0; red[w][1] = c1; red[w][2] = d0; red[w][3] = d1; }
    __syncthreads();
    if (tid == 0) {
        CD[0] = red[0][0] + red[1][0] + red[2][0] + red[3][0];
        CD[1] = red[0][1] + red[1][1] + red[2][1] + red[3][1];
        CD[2] = red[0][2] + red[1][2] + red[2][2] + red[3][2];
        CD[3] = red[0][3] + red[1][3] + red[2][3] + red[3][3];
    }
}

__global__ __launch_bounds__(256) void conv_ln_proj_kernel(
    const float* __restrict__ x, const float* __restrict__ cw,
    const float* __restrict__ cb, const float* __restrict__ lng,
    const float* __restrict__ pw, const float* __restrict__ pb,
    const float* __restrict__ CD, float* __restrict__ probs,
    int* __restrict__ gout)
{
    __shared__ float Xl[DSTEP][66];
    __shared__ float Bl[3][DSTEP][CCH];
    __shared__ float Sl[ROWS][4];

    int tid = threadIdx.x;
    int blk = blockIdx.x;
    int b  = blk >> 5;
    int n0 = (blk & 31) * ROWS;
    int rg = tid >> 5;
    int cg = tid & 31;
    int sr = tid >> 2;
    int sq = tid & 3;
    const float* xb = x + (size_t)b * Nsz * Dsz;

    float s0[8], s2[8], sa[8], sb[8];
    #pragma unroll
    for (int i = 0; i < 8; ++i) { s0[i] = 0.f; s2[i] = 0.f; sa[i] = 0.f; sb[i] = 0.f; }

    for (int cc = 0; cc < NCC; ++cc) {
        float cbv[4], gq0[4], gq1[4];
        {
            int hb = cc * CCH + cg * 4;
            #pragma unroll
            for (int j = 0; j < 4; ++j) {
                int h = hb + j;
                cbv[j] = cb[h];
                float gg = lng[h];
                gq0[j] = gg * pw[2 * h];
                gq1[j] = gg * pw[2 * h + 1];
            }
        }
        float acc[8][4];
        #pragma unroll
        for (int i = 0; i < 8; ++i)
            #pragma unroll
            for (int j = 0; j < 4; ++j) acc[i][j] = 0.f;

        for (int ds = 0; ds < Dsz / DSTEP; ++ds) {
            int d0 = ds * DSTEP;
            __syncthreads();
            {
                int n = n0 - 1 + sr;
                float4 v0 = make_float4(0.f, 0.f, 0.f, 0.f), v1 = v0;
                if ((unsigned)n < (unsigned)Nsz) {
                    const float* p = xb + (size_t)n * Dsz + d0 + sq * 8;
                    v0 = *(const float4*)p;
                    v1 = *(const float4*)(p + 4);
                }
                int dd = sq * 8;
                Xl[dd + 0][sr] = v0.x; Xl[dd + 1][sr] = v0.y;
                Xl[dd + 2][sr] = v0.z; Xl[dd + 3][sr] = v0.w;
                Xl[dd + 4][sr] = v1.x; Xl[dd + 5][sr] = v1.y;
                Xl[dd + 6][sr] = v1.z; Xl[dd + 7][sr] = v1.w;
                if (tid < 8) {
                    int r2 = 64 + (tid >> 2);
                    int q2 = tid & 3;
                    int n2 = n0 - 1 + r2;
                    float4 u0 = make_float4(0.f, 0.f, 0.f, 0.f), u1 = u0;
                    if ((unsigned)n2 < (unsigned)Nsz) {
                        const float* p2 = xb + (size_t)n2 * Dsz + d0 + q2 * 8;
                        u0 = *(const float4*)p2;
                        u1 = *(const float4*)(p2 + 4);
                    }
                    int dd2 = q2 * 8;
                    Xl[dd2 + 0][r2] = u0.x; Xl[dd2 + 1][r2] = u0.y;
                    Xl[dd2 + 2][r2] = u0.z; Xl[dd2 + 3][r2] = u0.w;
                    Xl[dd2 + 4][r2] = u1.x; Xl[dd2 + 5][r2] = u1.y;
                    Xl[dd2 + 6][r2] = u1.z; Xl[dd2 + 7][r2] = u1.w;
                }
            }
            {
                int hl = tid >> 1;
                int half = tid & 1;
                const float* p = cw + (size_t)(cc * CCH + hl) * K3D + (size_t)d0 * 3 + half * 48;
                #pragma unroll
                for (int mq = 0; mq < 12; ++mq) {
                    float4 v = *(const float4*)(p + mq * 4);
                    float vv[4] = { v.x, v.y, v.z, v.w };
                    #pragma unroll
                    for (int e = 0; e < 4; ++e) {
                        int c  = mq * 4 + e;
                        int dl = half * 16 + c / 3;
                        int kk = c % 3;
                        Bl[kk][dl][hl] = vv[e];
                    }
                }
            }
            __syncthreads();
            #pragma unroll 4
            for (int dd = 0; dd < DSTEP; ++dd) {
                float a[10];
                #pragma unroll
                for (int j = 0; j < 10; ++j) a[j] = Xl[dd][rg * 8 + j];
                #pragma unroll
                for (int kk = 0; kk < 3; ++kk) {
                    float4 bv = *(const float4*)&Bl[kk][dd][cg * 4];
                    #pragma unroll
                    for (int i = 0; i < 8; ++i) {
                        float av = a[i + kk];
                        acc[i][0] = fmaf(av, bv.x, acc[i][0]);
                        acc[i][1] = fmaf(av, bv.y, acc[i][1]);
                        acc[i][2] = fmaf(av, bv.z, acc[i][2]);
                        acc[i][3] = fmaf(av, bv.w, acc[i][3]);
                    }
                }
            }
        }
        #pragma unroll
        for (int i = 0; i < 8; ++i) {
            #pragma unroll
            for (int j = 0; j < 4; ++j) {
                float v = acc[i][j] + cbv[j];
                v = fmaxf(v, 0.f);
                s0[i] += v;
                s2[i] = fmaf(v, v, s2[i]);
                sa[i] = fmaf(v, gq0[j], sa[i]);
                sb[i] = fmaf(v, gq1[j], sb[i]);
            }
        }
    }
    #pragma unroll
    for (int i = 0; i < 8; ++i) {
        float v0 = s0[i], v2 = s2[i], va = sa[i], vb = sb[i];
        #pragma unroll
        for (int mm = 16; mm >= 1; mm >>= 1) {
            v0 += __shfl_xor(v0, mm, 64); v2 += __shfl_xor(v2, mm, 64);
            va += __shfl_xor(va, mm, 64); vb += __shfl_xor(vb, mm, 64);
        }
        if (cg == 0) {
            int rr = rg * 8 + i;
            Sl[rr][0] = v0; Sl[rr][1] = v2; Sl[rr][2] = va; Sl[rr][3] = vb;
        }
    }
    __syncthreads();
    if (tid < ROWS) {
        int rr = tid, n = n0 + rr;
        float S0 = Sl[rr][0], S2 = Sl[rr][1], Sa = Sl[rr][2], Sb = Sl[rr][3];
        float mu  = S0 * (1.0f / Hsz);
        float var = S2 * (1.0f / Hsz) - mu * mu;
        float rsq = 1.0f / sqrtf(var + 1e-5f);
        float p0 = fmaf(rsq, Sa - mu * CD[0], CD[2] + pb[0]);
        float p1 = fmaf(rsq, Sb - mu * CD[1], CD[3] + pb[1]);
        size_t ro = (size_t)(b * Nsz + n);
        probs[ro * 2]     = p0;
        probs[ro * 2 + 1] = p1;
        gout[ro] = (p1 > p0) ? 1 : 0;
    }
}

// ===========================================================================
// shared tail kernels
// ===========================================================================
__global__ __launch_bounds__(256) void bounds_kernel(
    const int* __restrict__ g, float* __restrict__ vlist, int* __restrict__ Kb)
{
    int b = blockIdx.x, tid = threadIdx.x;
    int base = tid * 8;
    int f[8]; float val[8]; int lsum = 0;
    #pragma unroll
    for (int u = 0; u < 8; ++u) {
        int i = base + u;
        int nz;
        if (i == Nsz - 1) nz = 1;
        else if (i == 0)  nz = 0;
        else              nz = (g[b * Nsz + i] == 0) ? 1 : 0;
        f[u] = nz;
        val[u] = (i == Nsz - 1) ? (float)Nsz : (float)(i + 1);
        lsum += nz;
    }
    int lane = tid & 63, w = tid >> 6;
    int sc = lsum;
    #pragma unroll
    for (int off = 1; off < 64; off <<= 1) {
        int t = __shfl_up(sc, off, 64);
        if (lane >= off) sc += t;
    }
    __shared__ int wsum[4];
    if (lane == 63) wsum[w] = sc;
    __syncthreads();
    int woff = 0;
    #pragma unroll
    for (int k = 0; k < 4; ++k) if (k < w) woff += wsum[k];
    int pos = woff + (sc - lsum);
    #pragma unroll
    for (int u = 0; u < 8; ++u) {
        if (f[u]) { vlist[b * Nsz + pos] = val[u]; pos++; }
    }
    if (tid == 255) Kb[b] = woff + sc;
}

__global__ __launch_bounds__(256) void fill_kernel(
    const float* __restrict__ vlist, const int* __restrict__ Kb,
    float* __restrict__ mat)
{
    int blk = blockIdx.x;
    int b = blk >> 11, j = blk & 2047;
    int K = Kb[b];
    float c = (j < K) ? vlist[b * Nsz + j] : 0.0f;
    float a = (j == 0) ? 0.0f : vlist[b * Nsz + j - 1];
    int tc = threadIdx.x * 8;
    float o[8];
    #pragma unroll
    for (int e = 0; e < 8; ++e) {
        float t = (float)(tc + e + 1);
        o[e] = (t > a && t <= c) ? 1.0f : 0.0f;
    }
    float4* p = (float4*)(mat + (size_t)blk * Nsz + tc);
    p[0] = make_float4(o[0], o[1], o[2], o[3]);
    p[1] = make_float4(o[4], o[5], o[6], o[7]);
}

// ===========================================================================
extern "C" void kernel_launch(void* const* d_in, const int* in_sizes, int n_in,
                              void* d_out, int out_size, void* d_ws, size_t ws_size,
                              hipStream_t stream)
{
    const float* x      = (const float*)d_in[0];
    const float* conv_w = (const float*)d_in[1];
    const float* conv_b = (const float*)d_in[2];
    const float* ln_g   = (const float*)d_in[3];
    const float* ln_b   = (const float*)d_in[4];
    const float* proj_w = (const float*)d_in[5];
    const float* proj_b = (const float*)d_in[6];

    float* out = (float*)d_out;
    char*  wsb = (char*)d_ws;

    // fast-path workspace layout
    size_t cur = 0;
    auto take = [&](size_t b) { size_t r = cur; cur = (cur + b + 255) & ~(size_t)255; return r; };
    size_t oCD  = take(16);
    size_t oGQ0 = take(Hsz * 4);
    size_t oGQ1 = take(Hsz * 4);
    size_t oKb  = take(32);
    size_t oG   = take((size_t)Bsz * Nsz * 4);
    size_t oV   = take((size_t)Bsz * Nsz * 4);
    size_t oPart= take((size_t)Bsz * Nsz * 64 * 4);
    size_t oXh  = take((size_t)Bsz * 16 * 4 * 2050 * 16);   // xs hi (q-major)
    size_t oXl  = take((size_t)Bsz * 16 * 4 * 2050 * 16);   // xs lo
    size_t oWh  = take((size_t)48 * 4 * 1024 * 16);         // ws hi
    size_t oWl  = take((size_t)48 * 4 * 1024 * 16);         // ws lo
    bool fast = ws_size >= cur;

    if (fast) {
        float* CD    = (float*)(wsb + oCD);
        float* gq0   = (float*)(wsb + oGQ0);
        float* gq1   = (float*)(wsb + oGQ1);
        int*   Kb    = (int*)  (wsb + oKb);
        int*   g     = (int*)  (wsb + oG);
        float* vlist = (float*)(wsb + oV);
        float* part  = (float*)(wsb + oPart);
        unsigned short* xsh = (unsigned short*)(wsb + oXh);
        unsigned short* xsl = (unsigned short*)(wsb + oXl);
        unsigned short* wsh = (unsigned short*)(wsb + oWh);
        unsigned short* wsl = (unsigned short*)(wsb + oWl);

        prep_kernel<<<197, 256, 0, stream>>>(conv_w, wsh, wsl, ln_g, ln_b, proj_w, CD, gq0, gq1);
        convert_x_kernel<<<Bsz * 2050 / 4, 256, 0, stream>>>(x, xsh, xsl);
        gemm6_kernel<<<(Bsz * Nsz / 128) * (Hsz / 128), 256, 0, stream>>>(
            xsh, xsl, wsh, wsl, conv_b, gq0, gq1, part);
        probs_kernel<<<Bsz * Nsz / 256, 256, 0, stream>>>(part, CD, proj_b, out, g);
        bounds_kernel<<<Bsz, 256, 0, stream>>>(g, vlist, Kb);
        fill_kernel<<<Bsz * Nsz, 256, 0, stream>>>(vlist, Kb, out + (size_t)Bsz * Nsz * 2);
    } else {
        // round-1 fallback layout
        float* wf  = (float*)d_ws;
        int*   wi  = (int*)d_ws;
        float* CD    = wf;
        int*   Kb    = wi + 4;
        int*   g     = wi + 16;
        float* vlist = wf + 16 + Bsz * Nsz;

        consts_kernel<<<1, 256, 0, stream>>>(ln_g, ln_b, proj_w, CD);
        conv_ln_proj_kernel<<<Bsz * Nsz / ROWS, 256, 0, stream>>>(
            x, conv_w, conv_b, ln_g, proj_w, proj_b, CD, out, g);
        bounds_kernel<<<Bsz, 256, 0, stream>>>(g, vlist, Kb);
        fill_kernel<<<Bsz * Nsz, 256, 0, stream>>>(vlist, Kb, out + (size_t)Bsz * Nsz * 2);
    }
}

// Round 7
// 182.940 us; speedup vs baseline: 1.1367x; 1.0985x over previous
//
#include <hip/hip_runtime.h>

#define Bsz 8
#define Nsz 2048
#define Dsz 512
#define Hsz 1024
#define K3D 1536   // 3*Dsz

typedef __attribute__((ext_vector_type(8))) short short8;
typedef __attribute__((ext_vector_type(4))) float f32x4;

// ---------------------------------------------------------------------------
// helpers
// ---------------------------------------------------------------------------
static __device__ __forceinline__ unsigned short f2bf(float f) {
    unsigned u = __builtin_bit_cast(unsigned, f);
    unsigned r = (u + 0x7FFFu + ((u >> 16) & 1u)) >> 16;   // RNE
    return (unsigned short)r;
}
static __device__ __forceinline__ float bf2f(unsigned short u) {
    return __builtin_bit_cast(float, (unsigned)u << 16);
}
static __device__ __forceinline__ void gld16(const void* g, void* l) {
    __builtin_amdgcn_global_load_lds(
        (const __attribute__((address_space(1))) void*)g,
        (__attribute__((address_space(3))) void*)l, 16, 0, 0);
}

// ===========================================================================
// FAST PATH
// ===========================================================================

// prep: convert_w (blocks 0..191) + consts (block 192) + colconst (193..196)
__global__ __launch_bounds__(256) void prep_kernel(
    const float* __restrict__ cw, unsigned short* __restrict__ wsh,
    unsigned short* __restrict__ wsl,
    const float* __restrict__ lng, const float* __restrict__ lnb,
    const float* __restrict__ pw, float* __restrict__ CD,
    float* __restrict__ gq0, float* __restrict__ gq1)
{
    __shared__ float red[4][4];
    int blk = blockIdx.x, tid = threadIdx.x;
    if (blk < 192) {
        // conv_w [H][D][3] fp32 -> q-major bf16 hi/lo: ws[s48][q4][h1024][16B]
        int gid = blk * 256 + tid;                   // 0..49151
        int s = gid >> 10, h = gid & 1023;
        int t = s >> 4, c = s & 15;
        const float* src = cw + (size_t)h * K3D + (size_t)c * 96 + t;
        short hv[32], lv[32];
        #pragma unroll
        for (int j = 0; j < 32; ++j) {
            float v = src[3 * j];
            unsigned short hi = f2bf(v);
            hv[j] = (short)hi;
            lv[j] = (short)f2bf(v - bf2f(hi));
        }
        #pragma unroll
        for (int m = 0; m < 4; ++m) {
            size_t dst = (((size_t)s * 4 + m) * 1024 + h) * 16;
            *(short8*)((char*)wsh + dst) = *(short8*)&hv[m * 8];
            *(short8*)((char*)wsl + dst) = *(short8*)&lv[m * 8];
        }
    } else if (blk == 192) {
        float c0 = 0.f, c1 = 0.f, d0 = 0.f, d1 = 0.f;
        for (int h = tid; h < Hsz; h += 256) {
            float g = lng[h], b = lnb[h];
            float w0 = pw[2 * h], w1 = pw[2 * h + 1];
            c0 = fmaf(g, w0, c0); c1 = fmaf(g, w1, c1);
            d0 = fmaf(b, w0, d0); d1 = fmaf(b, w1, d1);
        }
        #pragma unroll
        for (int m = 32; m >= 1; m >>= 1) {
            c0 += __shfl_xor(c0, m, 64); c1 += __shfl_xor(c1, m, 64);
            d0 += __shfl_xor(d0, m, 64); d1 += __shfl_xor(d1, m, 64);
        }
        int w = tid >> 6;
        if ((tid & 63) == 0) { red[w][0] = c0; red[w][1] = c1; red[w][2] = d0; red[w][3] = d1; }
        __syncthreads();
        if (tid == 0) {
            CD[0] = red[0][0] + red[1][0] + red[2][0] + red[3][0];
            CD[1] = red[0][1] + red[1][1] + red[2][1] + red[3][1];
            CD[2] = red[0][2] + red[1][2] + red[2][2] + red[3][2];
            CD[3] = red[0][3] + red[1][3] + red[2][3] + red[3][3];
        }
    } else {
        int h = (blk - 193) * 256 + tid;
        float g = lng[h];
        gq0[h] = g * pw[2 * h];
        gq1[h] = g * pw[2 * h + 1];
    }
}

// x (fp32 [B][N][D]) -> q-major bf16 hi/lo: xs[b][c16][q4][row2050][16B].
__global__ __launch_bounds__(256) void convert_x_kernel(
    const float* __restrict__ x, unsigned short* __restrict__ xsh,
    unsigned short* __restrict__ xsl)
{
    int tid = threadIdx.x;
    int r = blockIdx.x * 4 + (tid >> 6);         // padded row id 0..16399
    int e = tid & 63;                            // 8 elems each
    int b  = r / 2050;
    int rp = r - b * 2050;
    int c  = e >> 2;                             // k0-chunk 0..15
    int qq = e & 3;                              // k-quarter 0..3
    size_t dst = ((((size_t)b * 16 + c) * 4 + qq) * 2050 + rp) * 16;
    short8 hv, lv;
    if (rp == 0 || rp == 2049) {
        #pragma unroll
        for (int u = 0; u < 8; ++u) { hv[u] = 0; lv[u] = 0; }
    } else {
        const float* p = x + ((size_t)b * Nsz + (rp - 1)) * Dsz + e * 8;
        float4 v0 = *(const float4*)p;
        float4 v1 = *(const float4*)(p + 4);
        float vv[8] = { v0.x, v0.y, v0.z, v0.w, v1.x, v1.y, v1.z, v1.w };
        #pragma unroll
        for (int u = 0; u < 8; ++u) {
            unsigned short h = f2bf(vv[u]);
            hv[u] = (short)h;
            lv[u] = (short)f2bf(vv[u] - bf2f(h));
        }
    }
    *(short8*)((char*)xsh + dst) = hv;
    *(short8*)((char*)xsl + dst) = lv;
}

// Fused bf16x3 GEMM, 256x256 tile, 8 waves (2M x 4N, per-wave 128x64), BK=32,
// 48 steps (s: tap t = s>>4, chunk c = s&15 — same order as prior rounds).
// LDS: 2 x 64KB buffers; each buffer {Ah,Al,Bh,Bl} regions of [q4][256][16B].
// Staging: waves 0-3 stage A plane q=w (hi+lo), waves 4-7 stage B plane q=w-4;
// 8 gld16/wave/step, all lane-linear (1KB contiguous per instruction).
// Pipeline: STAGE(next) -> vmcnt(8) -> barrier -> ds_read+96 MFMA -> barrier.
__global__ __launch_bounds__(512, 2) void gemm7_kernel(
    const unsigned short* __restrict__ xsh, const unsigned short* __restrict__ xsl,
    const unsigned short* __restrict__ wsh, const unsigned short* __restrict__ wsl,
    const float* __restrict__ cb, const float* __restrict__ gq0,
    const float* __restrict__ gq1, float* __restrict__ part)
{
    __shared__ __align__(16) char lds[131072];

    int tid = threadIdx.x;
    // XCD-aware swizzle (256 blocks, 8 XCDs -> 32/XCD): each XCD gets 8
    // complete A-panel groups (same mt, all 4 ntb consecutive).
    int swz = (blockIdx.x & 7) * 32 + (blockIdx.x >> 3);
    int mt  = swz >> 2;            // 0..63 row tile
    int ntb = swz & 3;             // 0..3  col tile
    int bb  = mt >> 3;             // batch
    int n0  = (mt & 7) * 256;      // padded-row base
    int n0c = ntb * 256;           // col base
    int n0g = bb * Nsz + (mt & 7) * 256;  // output row base

    int l = tid & 63, w = tid >> 6;    // lane, wave 0..7
    int wr = w >> 2, wc = w & 3;       // wave quadrant: row half, col quarter
    int r = l & 15, qq = l >> 4;
    int aoff_r = qq * 4096 + (wr * 128 + r) * 16;
    int boff_r = qq * 4096 + (wc * 64 + r) * 16;

    // staging source bases (lane-linear)
    const char* pAh = (const char*)xsh + (size_t)bb * 2099200 + (w & 3) * 32800 + (size_t)(n0 + l) * 16;
    const char* pAl = (const char*)xsl + (size_t)bb * 2099200 + (w & 3) * 32800 + (size_t)(n0 + l) * 16;
    const char* pBh = (const char*)wsh + (w & 3) * 16384 + (size_t)(n0c + l) * 16;
    const char* pBl = (const char*)wsl + (w & 3) * 16384 + (size_t)(n0c + l) * 16;

    f32x4 acc[8][4];
    #pragma unroll
    for (int i = 0; i < 8; ++i)
        #pragma unroll
        for (int j = 0; j < 4; ++j) acc[i][j] = (f32x4){0.f, 0.f, 0.f, 0.f};

// stage step sn into buffer lb: 8 gld16 per wave
#define STAGE(lb, sn) do {                                                     \
    if (w < 4) {                                                               \
        size_t ao = (size_t)(((sn) & 15) * 131200 + ((sn) >> 4) * 16);         \
        _Pragma("unroll") for (int g = 0; g < 4; ++g) {                        \
            gld16(pAh + ao + g * 1024, (lb) +         w * 4096 + g * 1024);    \
            gld16(pAl + ao + g * 1024, (lb) + 16384 + w * 4096 + g * 1024);    \
        }                                                                      \
    } else {                                                                   \
        size_t bo = (size_t)(sn) * 65536;                                      \
        _Pragma("unroll") for (int g = 0; g < 4; ++g) {                        \
            gld16(pBh + bo + g * 1024, (lb) + 32768 + (w - 4) * 4096 + g * 1024); \
            gld16(pBl + bo + g * 1024, (lb) + 49152 + (w - 4) * 4096 + g * 1024); \
        }                                                                      \
    }                                                                          \
} while (0)

    // prologue
    STAGE(lds, 0);

    for (int s = 0; s < 48; ++s) {
        char* cur = lds + (s & 1) * 65536;
        if (s < 47) {
            STAGE(lds + ((s + 1) & 1) * 65536, s + 1);
            asm volatile("s_waitcnt vmcnt(8)" ::: "memory");  // cur's 8 done; next in flight
        } else {
            asm volatile("s_waitcnt vmcnt(0)" ::: "memory");
        }
        __builtin_amdgcn_s_barrier();
        asm volatile("" ::: "memory");

        short8 bh[4], bl[4];
        #pragma unroll
        for (int j = 0; j < 4; ++j) {
            bh[j] = *(const short8*)(cur + 32768 + boff_r + j * 256);
            bl[j] = *(const short8*)(cur + 49152 + boff_r + j * 256);
        }
        #pragma unroll
        for (int mh = 0; mh < 2; ++mh) {
            short8 ah[4], al[4];
            #pragma unroll
            for (int i = 0; i < 4; ++i) {
                ah[i] = *(const short8*)(cur +         aoff_r + (mh * 4 + i) * 256);
                al[i] = *(const short8*)(cur + 16384 + aoff_r + (mh * 4 + i) * 256);
            }
            __builtin_amdgcn_s_setprio(1);
            #pragma unroll
            for (int i = 0; i < 4; ++i)
                #pragma unroll
                for (int j = 0; j < 4; ++j) {
                    acc[mh*4+i][j] = __builtin_amdgcn_mfma_f32_16x16x32_bf16(ah[i], bh[j], acc[mh*4+i][j], 0, 0, 0);
                    acc[mh*4+i][j] = __builtin_amdgcn_mfma_f32_16x16x32_bf16(ah[i], bl[j], acc[mh*4+i][j], 0, 0, 0);
                    acc[mh*4+i][j] = __builtin_amdgcn_mfma_f32_16x16x32_bf16(al[i], bh[j], acc[mh*4+i][j], 0, 0, 0);
                }
            __builtin_amdgcn_s_setprio(0);
        }
        __builtin_amdgcn_s_barrier();   // all reads of cur done before it is re-staged
    }
#undef STAGE

    // epilogue: bias + relu + per-row stats over this wave's 64 cols.
    // 16 column-slots per row (ascending 64-col groups): slot = ntb*16 + wc*4.
    float cbv[4], g0v[4], g1v[4];
    #pragma unroll
    for (int j = 0; j < 4; ++j) {
        int col = n0c + wc * 64 + j * 16 + r;
        cbv[j] = cb[col]; g0v[j] = gq0[col]; g1v[j] = gq1[col];
    }
    int slot = ntb * 16 + wc * 4;
    #pragma unroll
    for (int m = 0; m < 8; ++m) {
        #pragma unroll
        for (int reg = 0; reg < 4; ++reg) {
            float v0 = 0.f, v2 = 0.f, va = 0.f, vb = 0.f;
            #pragma unroll
            for (int j = 0; j < 4; ++j) {
                float v = acc[m][j][reg] + cbv[j];
                v = fmaxf(v, 0.f);
                v0 += v;
                v2 = fmaf(v, v, v2);
                va = fmaf(v, g0v[j], va);
                vb = fmaf(v, g1v[j], vb);
            }
            #pragma unroll
            for (int msk = 1; msk < 16; msk <<= 1) {
                v0 += __shfl_xor(v0, msk, 64); v2 += __shfl_xor(v2, msk, 64);
                va += __shfl_xor(va, msk, 64); vb += __shfl_xor(vb, msk, 64);
            }
            if (r == 0) {
                int rowg = n0g + wr * 128 + m * 16 + qq * 4 + reg;
                *(f32x4*)(part + (size_t)rowg * 64 + slot) = (f32x4){v0, v2, va, vb};
            }
        }
    }
}

// finish LN + proj + argmax per row (deterministic reduction over 16 slots)
__global__ __launch_bounds__(256) void probs_kernel(
    const float* __restrict__ part, const float* __restrict__ CD,
    const float* __restrict__ pb, float* __restrict__ probs,
    int* __restrict__ gout)
{
    int row = blockIdx.x * 256 + threadIdx.x;
    float S0 = 0.f, S2 = 0.f, Sa = 0.f, Sb = 0.f;
    const float4* p = (const float4*)(part + (size_t)row * 64);
    #pragma unroll
    for (int c = 0; c < 16; ++c) {
        float4 v = p[c];
        S0 += v.x; S2 += v.y; Sa += v.z; Sb += v.w;
    }
    float mu  = S0 * (1.0f / Hsz);
    float var = S2 * (1.0f / Hsz) - mu * mu;
    float rsq = 1.0f / sqrtf(var + 1e-5f);
    float p0 = fmaf(rsq, Sa - mu * CD[0], CD[2] + pb[0]);
    float p1 = fmaf(rsq, Sb - mu * CD[1], CD[3] + pb[1]);
    probs[(size_t)row * 2]     = p0;
    probs[(size_t)row * 2 + 1] = p1;
    gout[row] = (p1 > p0) ? 1 : 0;
}

// ===========================================================================
// FALLBACK PATH (round-1 kernel, known-passing)
// ===========================================================================
#define ROWS 64
#define CCH 128
#define NCC (Hsz / CCH)
#define DSTEP 32

__global__ __launch_bounds__(256) void consts_kernel(
    const float* __restrict__ lng, const float* __restrict__ lnb,
    const float* __restrict__ pw, float* __restrict__ CD)
{
    int tid = threadIdx.x;
    float c0 = 0.f, c1 = 0.f, d0 = 0.f, d1 = 0.f;
    for (int h = tid; h < Hsz; h += 256) {
        float g = lng[h], b = lnb[h];
        float w0 = pw[2 * h], w1 = pw[2 * h + 1];
        c0 = fmaf(g, w0, c0); c1 = fmaf(g, w1, c1);
        d0 = fmaf(b, w0, d0); d1 = fmaf(b, w1, d1);
    }
    #pragma unroll
    for (int m = 32; m >= 1; m >>= 1) {
        c0 += __shfl_xor(c0, m, 64); c1 += __shfl_xor(c1, m, 64);
        d0 += __shfl_xor(d0, m, 64); d1 += __shfl_xor(d1, m, 64);
    }
    __shared__ float red[4][4];
    int w = tid >> 6;
    if ((tid & 63) == 0) { red[w][0] = c0; red[w][1] = c1; red[w][2] = d0; red[w][3] = d1; }
    __syncthreads();
    if (tid == 0) {
        CD[0] = red[0][0] + red[1][0] + red[2][0] + red[3][0];
        CD[1] = red[0][1] + red[1][1] + red[2][1] + red[3][1];
        CD[2] = red[0][2] + red[1][2] + red[2][2] + red[3][2];
        CD[3] = red[0][3] + red[1][3] + red[2][3] + red[3][3];
    }
}

__global__ __launch_bounds__(256) void conv_ln_proj_kernel(
    const float* __restrict__ x, const float* __restrict__ cw,
    const float* __restrict__ cb, const float* __restrict__ lng,
    const float* __restrict__ pw, const float* __restrict__ pb,
    const float* __restrict__ CD, float* __restrict__ probs,
    int* __restrict__ gout)
{
    __shared__ float Xl[DSTEP][66];
    __shared__ float Bl[3][DSTEP][CCH];
    __shared__ float Sl[ROWS][4];

    int tid = threadIdx.x;
    int blk = blockIdx.x;
    int b  = blk >> 5;
    int n0 = (blk & 31) * ROWS;
    int rg = tid >> 5;
    int cg = tid & 31;
    int sr = tid >> 2;
    int sq = tid & 3;
    const float* xb = x + (size_t)b * Nsz * Dsz;

    float s0[8], s2[8], sa[8], sb[8];
    #pragma unroll
    for (int i = 0; i < 8; ++i) { s0[i] = 0.f; s2[i] = 0.f; sa[i] = 0.f; sb[i] = 0.f; }

    for (int cc = 0; cc < NCC; ++cc) {
        float cbv[4], gq0[4], gq1[4];
        {
            int hb = cc * CCH + cg * 4;
            #pragma unroll
            for (int j = 0; j < 4; ++j) {
                int h = hb + j;
                cbv[j] = cb[h];
                float gg = lng[h];
                gq0[j] = gg * pw[2 * h];
                gq1[j] = gg * pw[2 * h + 1];
            }
        }
        float acc[8][4];
        #pragma unroll
        for (int i = 0; i < 8; ++i)
            #pragma unroll
            for (int j = 0; j < 4; ++j) acc[i][j] = 0.f;

        for (int ds = 0; ds < Dsz / DSTEP; ++ds) {
            int d0 = ds * DSTEP;
            __syncthreads();
            {
                int n = n0 - 1 + sr;
                float4 v0 = make_float4(0.f, 0.f, 0.f, 0.f), v1 = v0;
                if ((unsigned)n < (unsigned)Nsz) {
                    const float* p = xb + (size_t)n * Dsz + d0 + sq * 8;
                    v0 = *(const float4*)p;
                    v1 = *(const float4*)(p + 4);
                }
                int dd = sq * 8;
                Xl[dd + 0][sr] = v0.x; Xl[dd + 1][sr] = v0.y;
                Xl[dd + 2][sr] = v0.z; Xl[dd + 3][sr] = v0.w;
                Xl[dd + 4][sr] = v1.x; Xl[dd + 5][sr] = v1.y;
                Xl[dd + 6][sr] = v1.z; Xl[dd + 7][sr] = v1.w;
                if (tid < 8) {
                    int r2 = 64 + (tid >> 2);
                    int q2 = tid & 3;
                    int n2 = n0 - 1 + r2;
                    float4 u0 = make_float4(0.f, 0.f, 0.f, 0.f), u1 = u0;
                    if ((unsigned)n2 < (unsigned)Nsz) {
                        const float* p2 = xb + (size_t)n2 * Dsz + d0 + q2 * 8;
                        u0 = *(const float4*)p2;
                        u1 = *(const float4*)(p2 + 4);
                    }
                    int dd2 = q2 * 8;
                    Xl[dd2 + 0][r2] = u0.x; Xl[dd2 + 1][r2] = u0.y;
                    Xl[dd2 + 2][r2] = u0.z; Xl[dd2 + 3][r2] = u0.w;
                    Xl[dd2 + 4][r2] = u1.x; Xl[dd2 + 5][r2] = u1.y;
                    Xl[dd2 + 6][r2] = u1.z; Xl[dd2 + 7][r2] = u1.w;
                }
            }
            {
                int hl = tid >> 1;
                int half = tid & 1;
                const float* p = cw + (size_t)(cc * CCH + hl) * K3D + (size_t)d0 * 3 + half * 48;
                #pragma unroll
                for (int mq = 0; mq < 12; ++mq) {
                    float4 v = *(const float4*)(p + mq * 4);
                    float vv[4] = { v.x, v.y, v.z, v.w };
                    #pragma unroll
                    for (int e = 0; e < 4; ++e) {
                        int c  = mq * 4 + e;
                        int dl = half * 16 + c / 3;
                        int kk = c % 3;
                        Bl[kk][dl][hl] = vv[e];
                    }
                }
            }
            __syncthreads();
            #pragma unroll 4
            for (int dd = 0; dd < DSTEP; ++dd) {
                float a[10];
                #pragma unroll
                for (int j = 0; j < 10; ++j) a[j] = Xl[dd][rg * 8 + j];
                #pragma unroll
                for (int kk = 0; kk < 3; ++kk) {
                    float4 bv = *(const float4*)&Bl[kk][dd][cg * 4];
                    #pragma unroll
                    for (int i = 0; i < 8; ++i) {
                        float av = a[i + kk];
                        acc[i][0] = fmaf(av, bv.x, acc[i][0]);
                        acc[i][1] = fmaf(av, bv.y, acc[i][1]);
                        acc[i][2] = fmaf(av, bv.z, acc[i][2]);
                        acc[i][3] = fmaf(av, bv.w, acc[i][3]);
                    }
                }
            }
        }
        #pragma unroll
        for (int i = 0; i < 8; ++i) {
            #pragma unroll
            for (int j = 0; j < 4; ++j) {
                float v = acc[i][j] + cbv[j];
                v = fmaxf(v, 0.f);
                s0[i] += v;
                s2[i] = fmaf(v, v, s2[i]);
                sa[i] = fmaf(v, gq0[j], sa[i]);
                sb[i] = fmaf(v, gq1[j], sb[i]);
            }
        }
    }
    #pragma unroll
    for (int i = 0; i < 8; ++i) {
        float v0 = s0[i], v2 = s2[i], va = sa[i], vb = sb[i];
        #pragma unroll
        for (int mm = 16; mm >= 1; mm >>= 1) {
            v0 += __shfl_xor(v0, mm, 64); v2 += __shfl_xor(v2, mm, 64);
            va += __shfl_xor(va, mm, 64); vb += __shfl_xor(vb, mm, 64);
        }
        if (cg == 0) {
            int rr = rg * 8 + i;
            Sl[rr][0] = v0; Sl[rr][1] = v2; Sl[rr][2] = va; Sl[rr][3] = vb;
        }
    }
    __syncthreads();
    if (tid < ROWS) {
        int rr = tid, n = n0 + rr;
        float S0 = Sl[rr][0], S2 = Sl[rr][1], Sa = Sl[rr][2], Sb = Sl[rr][3];
        float mu  = S0 * (1.0f / Hsz);
        float var = S2 * (1.0f / Hsz) - mu * mu;
        float rsq = 1.0f / sqrtf(var + 1e-5f);
        float p0 = fmaf(rsq, Sa - mu * CD[0], CD[2] + pb[0]);
        float p1 = fmaf(rsq, Sb - mu * CD[1], CD[3] + pb[1]);
        size_t ro = (size_t)(b * Nsz + n);
        probs[ro * 2]     = p0;
        probs[ro * 2 + 1] = p1;
        gout[ro] = (p1 > p0) ? 1 : 0;
    }
}

// ===========================================================================
// shared tail kernels
// ===========================================================================
__global__ __launch_bounds__(256) void bounds_kernel(
    const int* __restrict__ g, float* __restrict__ vlist, int* __restrict__ Kb)
{
    int b = blockIdx.x, tid = threadIdx.x;
    int base = tid * 8;
    int f[8]; float val[8]; int lsum = 0;
    #pragma unroll
    for (int u = 0; u < 8; ++u) {
        int i = base + u;
        int nz;
        if (i == Nsz - 1) nz = 1;
        else if (i == 0)  nz = 0;
        else              nz = (g[b * Nsz + i] == 0) ? 1 : 0;
        f[u] = nz;
        val[u] = (i == Nsz - 1) ? (float)Nsz : (float)(i + 1);
        lsum += nz;
    }
    int lane = tid & 63, w = tid >> 6;
    int sc = lsum;
    #pragma unroll
    for (int off = 1; off < 64; off <<= 1) {
        int t = __shfl_up(sc, off, 64);
        if (lane >= off) sc += t;
    }
    __shared__ int wsum[4];
    if (lane == 63) wsum[w] = sc;
    __syncthreads();
    int woff = 0;
    #pragma unroll
    for (int k = 0; k < 4; ++k) if (k < w) woff += wsum[k];
    int pos = woff + (sc - lsum);
    #pragma unroll
    for (int u = 0; u < 8; ++u) {
        if (f[u]) { vlist[b * Nsz + pos] = val[u]; pos++; }
    }
    if (tid == 255) Kb[b] = woff + sc;
}

__global__ __launch_bounds__(256) void fill_kernel(
    const float* __restrict__ vlist, const int* __restrict__ Kb,
    float* __restrict__ mat)
{
    int blk = blockIdx.x;
    int b = blk >> 11, j = blk & 2047;
    int K = Kb[b];
    float c = (j < K) ? vlist[b * Nsz + j] : 0.0f;
    float a = (j == 0) ? 0.0f : vlist[b * Nsz + j - 1];
    int tc = threadIdx.x * 8;
    float o[8];
    #pragma unroll
    for (int e = 0; e < 8; ++e) {
        float t = (float)(tc + e + 1);
        o[e] = (t > a && t <= c) ? 1.0f : 0.0f;
    }
    float4* p = (float4*)(mat + (size_t)blk * Nsz + tc);
    p[0] = make_float4(o[0], o[1], o[2], o[3]);
    p[1] = make_float4(o[4], o[5], o[6], o[7]);
}

// ===========================================================================
extern "C" void kernel_launch(void* const* d_in, const int* in_sizes, int n_in,
                              void* d_out, int out_size, void* d_ws, size_t ws_size,
                              hipStream_t stream)
{
    const float* x      = (const float*)d_in[0];
    const float* conv_w = (const float*)d_in[1];
    const float* conv_b = (const float*)d_in[2];
    const float* ln_g   = (const float*)d_in[3];
    const float* ln_b   = (const float*)d_in[4];
    const float* proj_w = (const float*)d_in[5];
    const float* proj_b = (const float*)d_in[6];

    float* out = (float*)d_out;
    char*  wsb = (char*)d_ws;

    // fast-path workspace layout
    size_t cur = 0;
    auto take = [&](size_t b) { size_t r = cur; cur = (cur + b + 255) & ~(size_t)255; return r; };
    size_t oCD  = take(16);
    size_t oGQ0 = take(Hsz * 4);
    size_t oGQ1 = take(Hsz * 4);
    size_t oKb  = take(32);
    size_t oG   = take((size_t)Bsz * Nsz * 4);
    size_t oV   = take((size_t)Bsz * Nsz * 4);
    size_t oPart= take((size_t)Bsz * Nsz * 64 * 4);
    size_t oXh  = take((size_t)Bsz * 16 * 4 * 2050 * 16);   // xs hi (q-major)
    size_t oXl  = take((size_t)Bsz * 16 * 4 * 2050 * 16);   // xs lo
    size_t oWh  = take((size_t)48 * 4 * 1024 * 16);         // ws hi
    size_t oWl  = take((size_t)48 * 4 * 1024 * 16);         // ws lo
    bool fast = ws_size >= cur;

    if (fast) {
        float* CD    = (float*)(wsb + oCD);
        float* gq0   = (float*)(wsb + oGQ0);
        float* gq1   = (float*)(wsb + oGQ1);
        int*   Kb    = (int*)  (wsb + oKb);
        int*   g     = (int*)  (wsb + oG);
        float* vlist = (float*)(wsb + oV);
        float* part  = (float*)(wsb + oPart);
        unsigned short* xsh = (unsigned short*)(wsb + oXh);
        unsigned short* xsl = (unsigned short*)(wsb + oXl);
        unsigned short* wsh = (unsigned short*)(wsb + oWh);
        unsigned short* wsl = (unsigned short*)(wsb + oWl);

        prep_kernel<<<197, 256, 0, stream>>>(conv_w, wsh, wsl, ln_g, ln_b, proj_w, CD, gq0, gq1);
        convert_x_kernel<<<Bsz * 2050 / 4, 256, 0, stream>>>(x, xsh, xsl);
        gemm7_kernel<<<256, 512, 0, stream>>>(
            xsh, xsl, wsh, wsl, conv_b, gq0, gq1, part);
        probs_kernel<<<Bsz * Nsz / 256, 256, 0, stream>>>(part, CD, proj_b, out, g);
        bounds_kernel<<<Bsz, 256, 0, stream>>>(g, vlist, Kb);
        fill_kernel<<<Bsz * Nsz, 256, 0, stream>>>(vlist, Kb, out + (size_t)Bsz * Nsz * 2);
    } else {
        // round-1 fallback layout
        float* wf  = (float*)d_ws;
        int*   wi  = (int*)d_ws;
        float* CD    = wf;
        int*   Kb    = wi + 4;
        int*   g     = wi + 16;
        float* vlist = wf + 16 + Bsz * Nsz;

        consts_kernel<<<1, 256, 0, stream>>>(ln_g, ln_b, proj_w, CD);
        conv_ln_proj_kernel<<<Bsz * Nsz / ROWS, 256, 0, stream>>>(
            x, conv_w, conv_b, ln_g, proj_w, proj_b, CD, out, g);
        bounds_kernel<<<Bsz, 256, 0, stream>>>(g, vlist, Kb);
        fill_kernel<<<Bsz * Nsz, 256, 0, stream>>>(vlist, Kb, out + (size_t)Bsz * Nsz * 2);
    }
}